// Round 12
// baseline (689.157 us; speedup 1.0000x reference)
//
#include <hip/hip_runtime.h>
#include <hip/hip_fp16.h>

#define HDIM  50
#define G3    150
#define TSEQ  512
#define BATCH 2048
#define NB    8        // real batches per block (MFMA cols 0..7; 8..15 mirror col 7)
#define NLAY  4
#define NT    12       // A-row tiles: 0-3 = r, 4-7 = z, 8-11 = n (50 real rows / 64)
#define RING  4        // h ring-buffer depth per layer

typedef _Float16 f16x8 __attribute__((ext_vector_type(8)));
typedef float    f32x4 __attribute__((ext_vector_type(4)));

#define MFMA(a,b,c) __builtin_amdgcn_mfma_f32_16x16x32_f16((a),(b),(c),0,0,0)

// pack two f32 -> one u32 of 2 f16 (v_cvt_pkrtz_f16_f32)
static __device__ inline unsigned pk2(float a, float b) {
    return __builtin_bit_cast(unsigned, __builtin_amdgcn_cvt_pkrtz(a, b));
}

// Free-running wavefront pipeline: wave = layer, NO block barrier in the loop.
// Inter-layer handoff via depth-4 LDS ring + acquire/release flags; each wave
// runs its own t, hh-MFMAs issue before the x-poll to hide producer latency.
__global__ __launch_bounds__(256, 1)
void gru_async(const float* __restrict__ xin,
               const float* __restrict__ Wih0, const float* __restrict__ Whh0,
               const float* __restrict__ bih0, const float* __restrict__ bhh0,
               const float* __restrict__ WihL, const float* __restrict__ WhhL,
               const float* __restrict__ bihL, const float* __restrict__ bhhL,
               const float* __restrict__ fcw,  const float* __restrict__ fcb,
               float* __restrict__ out)
{
    const int tid  = threadIdx.x;
    const int lay  = tid >> 6;
    const int lane = tid & 63;
    const int lb   = lane & 15;
    const int lg   = lane >> 4;
    const int b0   = blockIdx.x * NB;
    const int lbc  = (lb < NB) ? lb : (NB - 1);

    // hsl[layer][slot][batchcol][k]; k=50 is the constant-1 bias slot (never overwritten)
    __shared__ __align__(16) _Float16 hsl[NLAY][RING][16][72];
    __shared__ float x_row[NB][516];
    __shared__ int prod[NLAY];   // h_l(t) published  <=> prod[l] >= t+1
    __shared__ int cons[NLAY];   // h_l(t) consumed   <=> cons[l] >= t+1

    const float* Wih = (lay==0) ? Wih0 : WihL + (size_t)(lay-1)*G3*HDIM;
    const float* Whh = (lay==0) ? Whh0 : WhhL + (size_t)(lay-1)*G3*HDIM;
    const float* bih = (lay==0) ? bih0 : bihL + (lay-1)*G3;
    const float* bhh = (lay==0) ? bhh0 : bhhL + (lay-1)*G3;

    // ---- A fragments (weights + biases folded at k==50), resident ----
    f16x8 a_hh[NT][2], a_ih[NT][2];
#pragma unroll
    for (int mt = 0; mt < NT; ++mt) {
        const int  ur = (mt & 3)*16 + lb;
        const bool rv = ur < HDIM;
        const int  gr = 50*(mt >> 2) + (rv ? ur : 0);
#pragma unroll
        for (int kt = 0; kt < 2; ++kt) {
            f16x8 fh, fi;
#pragma unroll
            for (int j = 0; j < 8; ++j) {
                const int k = 32*kt + 8*lg + j;
                float vh = 0.f, vi = 0.f;
                if (rv) {
                    if (k < HDIM)       vh = Whh[gr*HDIM + k];
                    else if (k == HDIM) vh = bhh[gr];
                    if (lay == 0) {
                        if (kt == 0 && k == 0)      vi = Wih[gr];
                        else if (kt == 0 && k == 1) vi = bih[gr];
                    } else {
                        if (k < HDIM)       vi = Wih[gr*HDIM + k];
                        else if (k == HDIM) vi = bih[gr];
                    }
                }
                fh[j] = (_Float16)vh; fi[j] = (_Float16)vi;
            }
            a_hh[mt][kt] = fh; a_ih[mt][kt] = fi;
        }
    }

    // ---- stage x; init all ring slots (h=0, bias slot = 1.0); init flags ----
    for (int k = tid; k < NB*TSEQ; k += 256)
        x_row[k >> 9][k & 511] = xin[(size_t)(b0 + (k >> 9))*TSEQ + (k & 511)];
    for (int k = tid; k < NLAY*RING*16*72; k += 256)
        ((_Float16*)hsl)[k] = (_Float16)(((k % 72) == HDIM) ? 1.f : 0.f);
    if (tid < NLAY) { prod[tid] = 0; cons[tid] = 0; }

    float hold[4][4];
#pragma unroll
    for (int m = 0; m < 4; ++m)
#pragma unroll
        for (int i = 0; i < 4; ++i) hold[m][i] = 0.f;

    f16x8 bx0{}, bx1{};
    if (lay == 0) {   // constant parts of layer-0 B-frag: [1]=1.0 on lg==0, rest 0
#pragma unroll
        for (int j = 0; j < 8; ++j) bx0[j] = (_Float16)0.f;
        if (lg == 0) bx0[1] = (_Float16)1.f;
    }
    const f32x4 Z4 = {0.f, 0.f, 0.f, 0.f};
    __syncthreads();   // staging done; last barrier until the epilogue

    for (int t = 0; t < TSEQ; ++t) {
        // ---- own h(t-1) fragments (slot (t-1)&3; t=0 reads init slot 3) ----
        const int rs = (t - 1) & (RING - 1);
        f16x8 bh0 = *(const f16x8*)&hsl[lay][rs][lb][8*lg];
        f16x8 bh1 = *(const f16x8*)&hsl[lay][rs][lb][32 + 8*lg];

        f32x4 acc[NT], accx[4];
#pragma unroll
        for (int mt = 0; mt < NT; ++mt) acc[mt] = MFMA(a_hh[mt][0], bh0, Z4);
#pragma unroll
        for (int mt = 0; mt < NT; ++mt) acc[mt] = MFMA(a_hh[mt][1], bh1, acc[mt]);

        // ---- acquire x(t) (hh-MFMAs above overlap the producer's tail) ----
        if (lay == 0) {
            if (lg == 0) bx0[0] = (_Float16)x_row[lbc][t];
        } else {
            const int want = t + 1;
            while (__hip_atomic_load(&prod[lay-1], __ATOMIC_ACQUIRE,
                                     __HIP_MEMORY_SCOPE_WORKGROUP) < want) {}
            const int xs = t & (RING - 1);
            bx0 = *(const f16x8*)&hsl[lay-1][xs][lb][8*lg];
            bx1 = *(const f16x8*)&hsl[lay-1][xs][lb][32 + 8*lg];
            if (lane == 0)
                __hip_atomic_store(&cons[lay-1], want, __ATOMIC_RELEASE,
                                   __HIP_MEMORY_SCOPE_WORKGROUP);
        }

#pragma unroll
        for (int mt = 0; mt < 8; ++mt) acc[mt] = MFMA(a_ih[mt][0], bx0, acc[mt]);
#pragma unroll
        for (int m = 0; m < 4; ++m)    accx[m] = MFMA(a_ih[8+m][0], bx0, Z4);
        if (lay != 0) {
#pragma unroll
            for (int mt = 0; mt < 8; ++mt) acc[mt] = MFMA(a_ih[mt][1], bx1, acc[mt]);
#pragma unroll
            for (int m = 0; m < 4; ++m)    accx[m] = MFMA(a_ih[8+m][1], bx1, accx[m]);
        }

        // ---- sigmoids for r (tiles 0-3) and z (tiles 4-7) ----
#pragma unroll
        for (int mt = 0; mt < 8; ++mt) {
#pragma unroll
            for (int i = 0; i < 4; ++i) {
                if (((mt & 3) == 3) && i >= 2) continue;   // rows >= 50
                acc[mt][i] = __builtin_amdgcn_rcpf(1.f + __expf(-acc[mt][i]));
            }
        }

        // ---- n gate + h update (all-register) ----
        float hp[4][4];
#pragma unroll
        for (int m = 0; m < 4; ++m) {
#pragma unroll
            for (int i = 0; i < 4; ++i) {
                if (m == 3 && i >= 2) { hp[m][i] = 0.f; continue; }
                const float r  = acc[m][i];
                const float z  = acc[4+m][i];
                const float vp = accx[m][i] + r * acc[8+m][i];
                const float e2 = __expf(2.f * vp);
                const float n  = 1.f - 2.f*__builtin_amdgcn_rcpf(e2 + 1.f);  // tanh
                const float h  = fmaf(z, hold[m][i] - n, n);                 // (1-z)n+zh
                hold[m][i] = h;
                hp[m][i] = h;
            }
        }

        // ---- backpressure: slot t&3 holds h(t-4); consumer must be done ----
        if (lay < NLAY-1 && t >= RING) {
            const int need = t - RING + 1;
            while (__hip_atomic_load(&cons[lay], __ATOMIC_ACQUIRE,
                                     __HIP_MEMORY_SCOPE_WORKGROUP) < need) {}
        }

        // ---- publish h(t): b64 writes (m=0..2), b32 (m=3, lg==0) ----
        {
            _Float16* hrow = &hsl[lay][t & (RING-1)][lb][0];
#pragma unroll
            for (int m = 0; m < 3; ++m) {
                uint2 q; q.x = pk2(hp[m][0], hp[m][1]);
                         q.y = pk2(hp[m][2], hp[m][3]);
                *(uint2*)&hrow[16*m + 4*lg] = q;
            }
            if (lg == 0) {   // rows 48,49
                *(unsigned*)&hrow[48] = pk2(hp[3][0], hp[3][1]);
            }
        }
        if (lane == 0)
            __hip_atomic_store(&prod[lay], t + 1, __ATOMIC_RELEASE,
                               __HIP_MEMORY_SCOPE_WORKGROUP);
    }

    __syncthreads();   // all layers done

    // ---- fused FC + sigmoid on layer-3 final h (t=511 -> slot 3) ----
    if (tid < NB) {
        float sacc = fcb[0];
#pragma unroll
        for (int j = 0; j < HDIM; ++j)
            sacc = fmaf((float)hsl[NLAY-1][(TSEQ-1) & (RING-1)][tid][j], fcw[j], sacc);
        out[b0 + tid] = __builtin_amdgcn_rcpf(1.f + __expf(-sacc));
    }
}

extern "C" void kernel_launch(void* const* d_in, const int* in_sizes, int n_in,
                              void* d_out, int out_size, void* d_ws, size_t ws_size,
                              hipStream_t stream) {
    const float* x     = (const float*)d_in[0];
    const float* W_ih0 = (const float*)d_in[1];
    const float* W_hh0 = (const float*)d_in[2];
    const float* b_ih0 = (const float*)d_in[3];
    const float* b_hh0 = (const float*)d_in[4];
    const float* W_ih  = (const float*)d_in[5];
    const float* W_hh  = (const float*)d_in[6];
    const float* b_ih  = (const float*)d_in[7];
    const float* b_hh  = (const float*)d_in[8];
    const float* fc_w  = (const float*)d_in[9];
    const float* fc_b  = (const float*)d_in[10];
    float* out = (float*)d_out;

    dim3 grid(BATCH / NB), block(256);
    gru_async<<<grid, block, 0, stream>>>(
        x, W_ih0, W_hh0, b_ih0, b_hh0,
        W_ih, W_hh, b_ih, b_hh, fc_w, fc_b, out);
}